// Round 1
// baseline (368.274 us; speedup 1.0000x reference)
//
#include <hip/hip_runtime.h>
#include <cstdint>
#include <cstddef>

typedef __attribute__((ext_vector_type(8))) _Float16 f16x8;
typedef __attribute__((ext_vector_type(16))) float f32x16;

#define LO_SCALE 2048.0f
#define LO_INV   (1.0f / 2048.0f)

union H8 { f16x8 v; _Float16 h[8]; };
union H4 { _Float16 h[4]; uint2 u; };

// ---------------------------------------------------------------------------
// Kernel C: layer-0 effective weights (fragment blob) + all effective biases
// w0blob layout per t: [nf(8)][part(2)][lane(64)*8 halves]  (1KB chunks)
// beff layout: [t][k(4)][256] fp32,  k=0: b0+hb0, k>=1: bh[k-1]+hb[k]
// ---------------------------------------------------------------------------
__global__ __launch_bounds__(256) void kc_small(
    const float* __restrict__ latents, const float* __restrict__ W0,
    const float* __restrict__ b0, const float* __restrict__ bh,
    const float* __restrict__ HW0, const float* __restrict__ HB,
    _Float16* __restrict__ w0blob, float* __restrict__ beff) {
  int id = blockIdx.x * 256 + threadIdx.x;
  if (id < 32768) {
    int t = id >> 10, rem = id & 1023;
    int r2 = rem & 127, part = r2 >> 6, lane = r2 & 63;
    int nf = rem >> 7;
    int o = nf * 32 + (lane & 31), kc = lane >> 5;
    const float* lat = latents + t * 256;
    H8 outv;
#pragma unroll
    for (int j = 0; j < 8; ++j) outv.h[j] = (_Float16)0.0f;
#pragma unroll
    for (int j = 0; j < 8; ++j) {
      int i = kc * 8 + j;
      if (i < 3) {
        const float* row = HW0 + (o * 3 + i) * 256;
        float s = W0[o * 3 + i];
        for (int k = 0; k < 256; k += 4)
          s += row[k] * lat[k] + row[k + 1] * lat[k + 1] +
               row[k + 2] * lat[k + 2] + row[k + 3] * lat[k + 3];
        _Float16 hi = (_Float16)s;
        outv.h[j] = part ? (_Float16)((s - (float)hi) * LO_SCALE) : hi;
      }
    }
    *(f16x8*)(w0blob + (size_t)id * 8) = outv.v;
  } else {
    int v = id - 32768;
    int t = v >> 10, k = (v >> 8) & 3, hm = v & 255;
    float base = (k == 0) ? b0[hm] : bh[(k - 1) * 256 + hm];
    const float* lat = latents + t * 256;
    const float* row = HB + (size_t)(k * 256 + hm) * 256;
    float s = base;
    for (int kk = 0; kk < 256; kk += 4)
      s += row[kk] * lat[kk] + row[kk + 1] * lat[kk + 1] +
           row[kk + 2] * lat[kk + 2] + row[kk + 3] * lat[kk + 3];
    beff[v] = s;
  }
}

// ---------------------------------------------------------------------------
// Kernel A: Weff[t][l][r] = Wh[l][r] + sum_m latents[t][m]*HWh[l][r][m]
// (r = o*256+i, 65536 rows/layer). GEMM M=rows, N=32 frames, K=256.
// Output split to fp16 hi + (lo*2048), plain [tl][r] layout (coalesced).
// Block: 128 rows x 32 frames, thread tile 4x4, K staged in 32-chunks (dbuf).
// ---------------------------------------------------------------------------
__global__ __launch_bounds__(256) void ka_weff(
    const float* __restrict__ latents, const float* __restrict__ Wh,
    const float* __restrict__ HWh,
    _Float16* __restrict__ whi, _Float16* __restrict__ wlo) {
  __shared__ float lat_s[32 * 260];
  __shared__ float As[2][128 * 36];
  int tid = threadIdx.x, bid = blockIdx.x;
  int l = bid >> 9;
  int row0 = (bid & 511) * 128;

#pragma unroll
  for (int q = 0; q < 8; ++q) {
    int f4 = q * 256 + tid;
    int f = f4 >> 6, c4 = f4 & 63;
    *(float4*)(lat_s + f * 260 + c4 * 4) = *(const float4*)(latents + f4 * 4);
  }
  const float* src = HWh + (size_t)l * 16777216 + (size_t)row0 * 256;
  float4 st[4];
  int rg = tid >> 3, fg = tid & 7;
  float acc[4][4];
#pragma unroll
  for (int a = 0; a < 4; ++a)
#pragma unroll
    for (int b = 0; b < 4; ++b) acc[a][b] = 0.f;

#pragma unroll
  for (int it = 0; it < 4; ++it) {
    int idx = it * 256 + tid, rr = idx >> 3, kq = idx & 7;
    st[it] = *(const float4*)(src + rr * 256 + kq * 4);
  }
#pragma unroll
  for (int it = 0; it < 4; ++it) {
    int idx = it * 256 + tid, rr = idx >> 3, kq = idx & 7;
    *(float4*)(As[0] + rr * 36 + kq * 4) = st[it];
  }
  __syncthreads();

  for (int kc = 0; kc < 8; ++kc) {
    if (kc < 7) {
#pragma unroll
      for (int it = 0; it < 4; ++it) {
        int idx = it * 256 + tid, rr = idx >> 3, kq = idx & 7;
        st[it] = *(const float4*)(src + rr * 256 + (kc + 1) * 32 + kq * 4);
      }
    }
    const float* ab = As[kc & 1];
#pragma unroll
    for (int k4 = 0; k4 < 8; ++k4) {
      float av[4][4], bv[4][4];
#pragma unroll
      for (int j = 0; j < 4; ++j)
        *(float4*)av[j] = *(const float4*)(ab + (rg * 4 + j) * 36 + k4 * 4);
#pragma unroll
      for (int j = 0; j < 4; ++j)
        *(float4*)bv[j] = *(const float4*)(lat_s + (fg * 4 + j) * 260 + kc * 32 + k4 * 4);
#pragma unroll
      for (int j = 0; j < 4; ++j)
#pragma unroll
        for (int jf = 0; jf < 4; ++jf)
#pragma unroll
          for (int e = 0; e < 4; ++e)
            acc[j][jf] += av[j][e] * bv[jf][e];
    }
    if (kc < 7) {
      int nb = (kc + 1) & 1;
#pragma unroll
      for (int it = 0; it < 4; ++it) {
        int idx = it * 256 + tid, rr = idx >> 3, kq = idx & 7;
        *(float4*)(As[nb] + rr * 36 + kq * 4) = st[it];
      }
    }
    __syncthreads();
  }

  float4 whv = *(const float4*)(Wh + l * 65536 + row0 + rg * 4);
  float wha[4];
  *(float4*)wha = whv;
#pragma unroll
  for (int jf = 0; jf < 4; ++jf) {
    int t = fg * 4 + jf;
    size_t base = ((size_t)(t * 3 + l) << 16) + (size_t)(row0 + rg * 4);
    H4 hh, ll;
#pragma unroll
    for (int j = 0; j < 4; ++j) {
      float w = acc[j][jf] + wha[j];
      _Float16 hi = (_Float16)w;
      hh.h[j] = hi;
      ll.h[j] = (_Float16)((w - (float)hi) * LO_SCALE);
    }
    *(uint2*)(whi + base) = hh.u;
    *(uint2*)(wlo + base) = ll.u;
  }
}

// ---------------------------------------------------------------------------
// Kernel A2: rearrange plain [tl][o*256+i] halves -> MFMA A-fragment blob
// whblob per (tl): [nf(8)][ks(16)][part(2)][lane(64)*8 halves]
//   element at lane,j: o = nf*32 + (lane&31), i = ks*16 + (lane>>5)*8 + j
// ---------------------------------------------------------------------------
__global__ __launch_bounds__(256) void ka2_blob(
    const _Float16* __restrict__ whi, const _Float16* __restrict__ wlo,
    _Float16* __restrict__ whblob) {
  __shared__ _Float16 a_s[32 * 264];
  int tid = threadIdx.x, bid = blockIdx.x;
  int part = bid & 1, nf = (bid >> 1) & 7, tl = bid >> 4;
  const _Float16* src = (part ? wlo : whi) + ((size_t)tl << 16) + nf * 8192;
  int rr = tid >> 3, sq = tid & 7;
#pragma unroll
  for (int m = 0; m < 4; ++m) {
    f16x8 v = *(const f16x8*)(src + rr * 256 + sq * 32 + m * 8);
    *(f16x8*)(a_s + rr * 264 + sq * 32 + m * 8) = v;
  }
  __syncthreads();
  _Float16* dst = whblob + (size_t)tl * 131072 + (size_t)(nf * 32 + part) * 512;
#pragma unroll
  for (int uu = 0; uu < 4; ++uu) {
    int unit = uu * 256 + tid;
    int ks = unit >> 6, lane = unit & 63;
    int r2 = lane & 31, i0 = ks * 16 + (lane >> 5) * 8;
    f16x8 v = *(const f16x8*)(a_s + r2 * 264 + i0);
    *(f16x8*)(dst + ks * 1024 + lane * 8) = v;
  }
}

// ---------------------------------------------------------------------------
// Kernel B: fused SIREN. Block = one frame x 64 pixels. 4 waves, each owns a
// 64-wide o-slice. Transposed GEMM: D[o][px] = sum_k Weff[o][k]*x[px][k] via
// mfma_f32_32x32x16_f16, split-fp16 (hh -> accA; hl + lh (lo pre-scaled 2048)
// -> accB; result = accA + accB/2048). x kept in LDS as hi/lo fp16 arrays.
// ---------------------------------------------------------------------------
__global__ __launch_bounds__(256, 2) void kb_siren(
    const float* __restrict__ coords, const _Float16* __restrict__ whblob,
    const _Float16* __restrict__ w0blob, const float* __restrict__ beff,
    const float* __restrict__ Wf, const float* __restrict__ bf,
    float* __restrict__ out) {
  __shared__ _Float16 xs_hi[64 * 264];
  __shared__ _Float16 xs_lo[64 * 264];
  __shared__ float wf_s[768];
  __shared__ float red[768];
  int tid = threadIdx.x;
  int bid0 = blockIdx.x;
  int bid = (bid0 & 7) * 256 + (bid0 >> 3);  // XCD swizzle: 4 frames per XCD
  int t = bid >> 6, tile = bid & 63;
  int wv = tid >> 6, lane = tid & 63, col = lane & 31, h = lane >> 5;

  if (tid < 192) *(float4*)(wf_s + tid * 4) = *(const float4*)(Wf + tid * 4);
  if (tid < 64) {
    const float* cp = coords + (size_t)(t * 4096 + tile * 64 + tid) * 3;
    float c0 = cp[0], c1 = cp[1], c2 = cp[2];
    H8 hv, lv, z;
#pragma unroll
    for (int j = 0; j < 8; ++j) { hv.h[j] = (_Float16)0.f; lv.h[j] = (_Float16)0.f; z.h[j] = (_Float16)0.f; }
    _Float16 h0 = (_Float16)c0, h1 = (_Float16)c1, h2 = (_Float16)c2;
    hv.h[0] = h0; hv.h[1] = h1; hv.h[2] = h2;
    lv.h[0] = (_Float16)((c0 - (float)h0) * LO_SCALE);
    lv.h[1] = (_Float16)((c1 - (float)h1) * LO_SCALE);
    lv.h[2] = (_Float16)((c2 - (float)h2) * LO_SCALE);
    *(f16x8*)(xs_hi + tid * 264) = hv.v;
    *(f16x8*)(xs_lo + tid * 264) = lv.v;
    *(f16x8*)(xs_hi + tid * 264 + 8) = z.v;
    *(f16x8*)(xs_lo + tid * 264 + 8) = z.v;
  }
  __syncthreads();

  f32x16 accA[2][2], accB[2][2];

  auto init_bias = [&](int bk) {
    const float* bp = beff + ((t * 4 + bk) << 8) + wv * 64 + h * 4;
#pragma unroll
    for (int fr = 0; fr < 2; ++fr)
#pragma unroll
      for (int rq = 0; rq < 4; ++rq) {
        float4 bvv = *(const float4*)(bp + fr * 32 + rq * 8);
        float ba[4];
        *(float4*)ba = bvv;
#pragma unroll
        for (int q = 0; q < 4; ++q) {
          accA[fr][0][rq * 4 + q] = ba[q];
          accA[fr][1][rq * 4 + q] = ba[q];
          accB[fr][0][rq * 4 + q] = 0.f;
          accB[fr][1][rq * 4 + q] = 0.f;
        }
      }
  };

  auto load_a = [&](const _Float16* blobL, int NS, int ks, f16x8 (&a)[2][2]) {
#pragma unroll
    for (int fr = 0; fr < 2; ++fr) {
      int nf = wv * 2 + fr;
      const _Float16* p = blobL + (size_t)((nf * NS + ks) * 2) * 512 + lane * 8;
      a[fr][0] = *(const f16x8*)p;
      a[fr][1] = *(const f16x8*)(p + 512);
    }
  };

  auto load_b = [&](int ks, f16x8 (&b)[2][2]) {
#pragma unroll
    for (int pf = 0; pf < 2; ++pf) {
      int off = (pf * 32 + col) * 264 + ks * 16 + h * 8;
      b[pf][0] = *(const f16x8*)(xs_hi + off);
      b[pf][1] = *(const f16x8*)(xs_lo + off);
    }
  };

  auto mfma12 = [&](f16x8 (&a)[2][2], f16x8 (&b)[2][2]) {
#pragma unroll
    for (int fr = 0; fr < 2; ++fr)
#pragma unroll
      for (int pf = 0; pf < 2; ++pf) {
        accA[fr][pf] = __builtin_amdgcn_mfma_f32_32x32x16_f16(a[fr][0], b[pf][0], accA[fr][pf], 0, 0, 0);
        accB[fr][pf] = __builtin_amdgcn_mfma_f32_32x32x16_f16(a[fr][0], b[pf][1], accB[fr][pf], 0, 0, 0);
        accB[fr][pf] = __builtin_amdgcn_mfma_f32_32x32x16_f16(a[fr][1], b[pf][0], accB[fr][pf], 0, 0, 0);
      }
  };

  // sine + split + in-register transpose (C rows=o -> B-frag k-contig) + store
  auto epilogue = [&]() {
#pragma unroll
    for (int fr = 0; fr < 2; ++fr)
#pragma unroll
      for (int pf = 0; pf < 2; ++pf)
#pragma unroll
        for (int r = 0; r < 16; ++r)
          accA[fr][pf][r] = __sinf(30.0f * (accA[fr][pf][r] + accB[fr][pf][r] * LO_INV));
    __syncthreads();  // all waves done reading xs for this layer
#pragma unroll
    for (int fr = 0; fr < 2; ++fr)
#pragma unroll
      for (int pf = 0; pf < 2; ++pf)
#pragma unroll
        for (int g = 0; g < 2; ++g) {
          float seq[8];
#pragma unroll
          for (int q = 0; q < 4; ++q) {
            float oa = accA[fr][pf][8 * g + q];       // rows 16g + q + 4h
            float ob = accA[fr][pf][8 * g + 4 + q];   // rows 16g + 8 + q + 4h
            float send = h ? oa : ob;
            float recv = __shfl_xor(send, 32, 64);
            seq[q]     = h ? recv : oa;
            seq[4 + q] = h ? ob : recv;
          }
          H8 hv, lv;
#pragma unroll
          for (int j = 0; j < 8; ++j) {
            _Float16 hi = (_Float16)seq[j];
            hv.h[j] = hi;
            lv.h[j] = (_Float16)((seq[j] - (float)hi) * LO_SCALE);
          }
          int off = (pf * 32 + col) * 264 + wv * 64 + fr * 32 + g * 16 + h * 8;
          *(f16x8*)(xs_hi + off) = hv.v;
          *(f16x8*)(xs_lo + off) = lv.v;
        }
    __syncthreads();
  };

  // ---- layer 0 (k=16, mostly zero-padded; coords staged in xs[.., 0..15])
  init_bias(0);
  {
    f16x8 a[2][2], b[2][2];
    load_a(w0blob + (size_t)t * 8192, 1, 0, a);
    load_b(0, b);
    mfma12(a, b);
  }
  epilogue();

  // ---- hidden layers
  for (int li = 0; li < 3; ++li) {
    init_bias(li + 1);
    const _Float16* bl = whblob + (size_t)(t * 3 + li) * 131072;
#pragma unroll
    for (int ks = 0; ks < 16; ++ks) {
      f16x8 a[2][2], b[2][2];
      load_a(bl, 16, ks, a);
      load_b(ks, b);
      mfma12(a, b);
    }
    epilogue();
  }

  // ---- final linear (3 outputs), VALU from LDS
  {
    float pc0 = 0.f, pc1 = 0.f, pc2 = 0.f;
    int px = tid & 63, kq = tid >> 6;
#pragma unroll
    for (int cc = 0; cc < 8; ++cc) {
      int k0 = kq * 64 + cc * 8;
      H8 hv, lv;
      hv.v = *(const f16x8*)(xs_hi + px * 264 + k0);
      lv.v = *(const f16x8*)(xs_lo + px * 264 + k0);
#pragma unroll
      for (int j = 0; j < 8; ++j) {
        float xv = (float)hv.h[j] + (float)lv.h[j] * LO_INV;
        pc0 += xv * wf_s[k0 + j];
        pc1 += xv * wf_s[256 + k0 + j];
        pc2 += xv * wf_s[512 + k0 + j];
      }
    }
    red[(kq * 64 + px) * 3 + 0] = pc0;
    red[(kq * 64 + px) * 3 + 1] = pc1;
    red[(kq * 64 + px) * 3 + 2] = pc2;
    __syncthreads();
    if (tid < 192) {
      int p2 = tid / 3, c = tid - p2 * 3;
      float s = red[p2 * 3 + c] + red[192 + p2 * 3 + c] +
                red[384 + p2 * 3 + c] + red[576 + p2 * 3 + c] + bf[c];
      out[(size_t)(t * 4096 + tile * 64 + p2) * 3 + c] = s;
    }
  }
}

// ---------------------------------------------------------------------------
extern "C" void kernel_launch(void* const* d_in, const int* in_sizes, int n_in,
                              void* d_out, int out_size, void* d_ws, size_t ws_size,
                              hipStream_t stream) {
  const float* coords  = (const float*)d_in[0];
  const float* latents = (const float*)d_in[1];
  const float* W0      = (const float*)d_in[2];
  const float* b0      = (const float*)d_in[3];
  const float* Wh      = (const float*)d_in[4];
  const float* bh      = (const float*)d_in[5];
  const float* Wf      = (const float*)d_in[6];
  const float* bf      = (const float*)d_in[7];
  const float* HW0     = (const float*)d_in[8];
  const float* HWh     = (const float*)d_in[9];
  const float* HB      = (const float*)d_in[10];
  float* outp = (float*)d_out;

  char* w = (char*)d_ws;
  _Float16* whi    = (_Float16*)w;                   // 6,291,456 halves
  _Float16* wlo    = whi + 6291456;                  // 6,291,456 halves
  _Float16* whblob = (_Float16*)(w + 25165824);      // 12,582,912 halves
  _Float16* w0blob = (_Float16*)(w + 50331648);      // 262,144 halves
  float*    beff   = (float*)(w + 50855936);         // 32,768 floats

  kc_small<<<256, 256, 0, stream>>>(latents, W0, b0, bh, HW0, HB, w0blob, beff);
  ka_weff<<<1536, 256, 0, stream>>>(latents, Wh, HWh, whi, wlo);
  ka2_blob<<<1536, 256, 0, stream>>>(whi, wlo, whblob);
  kb_siren<<<2048, 256, 0, stream>>>(coords, whblob, w0blob, beff, Wf, bf, outp);
}

// Round 2
// 246.423 us; speedup vs baseline: 1.4945x; 1.4945x over previous
//
#include <hip/hip_runtime.h>
#include <cstdint>
#include <cstddef>

typedef __attribute__((ext_vector_type(8))) _Float16 f16x8;
typedef __attribute__((ext_vector_type(16))) float f32x16;

#define LO_SCALE 2048.0f
#define LO_INV   (1.0f / 2048.0f)

union H8 { f16x8 v; _Float16 h[8]; };

// ---------------------------------------------------------------------------
// Kernel C: layer-0 effective weights (fragment blob) + all effective biases
// w0blob layout per t: [nf(8)][part(2)][lane(64)*8 halves]  (1KB chunks)
// beff layout: [t][k(4)][256] fp32,  k=0: b0+hb0, k>=1: bh[k-1]+hb[k]
// ---------------------------------------------------------------------------
__global__ __launch_bounds__(256) void kc_small(
    const float* __restrict__ latents, const float* __restrict__ W0,
    const float* __restrict__ b0, const float* __restrict__ bh,
    const float* __restrict__ HW0, const float* __restrict__ HB,
    _Float16* __restrict__ w0blob, float* __restrict__ beff) {
  int id = blockIdx.x * 256 + threadIdx.x;
  if (id < 32768) {
    int t = id >> 10, rem = id & 1023;
    int r2 = rem & 127, part = r2 >> 6, lane = r2 & 63;
    int nf = rem >> 7;
    int o = nf * 32 + (lane & 31), kc = lane >> 5;
    const float* lat = latents + t * 256;
    H8 outv;
#pragma unroll
    for (int j = 0; j < 8; ++j) outv.h[j] = (_Float16)0.0f;
#pragma unroll
    for (int j = 0; j < 8; ++j) {
      int i = kc * 8 + j;
      if (i < 3) {
        const float* row = HW0 + (o * 3 + i) * 256;
        float s = W0[o * 3 + i];
        for (int k = 0; k < 256; k += 4)
          s += row[k] * lat[k] + row[k + 1] * lat[k + 1] +
               row[k + 2] * lat[k + 2] + row[k + 3] * lat[k + 3];
        _Float16 hi = (_Float16)s;
        outv.h[j] = part ? (_Float16)((s - (float)hi) * LO_SCALE) : hi;
      }
    }
    *(f16x8*)(w0blob + (size_t)id * 8) = outv.v;
  } else {
    int v = id - 32768;
    int t = v >> 10, k = (v >> 8) & 3, hm = v & 255;
    float base = (k == 0) ? b0[hm] : bh[(k - 1) * 256 + hm];
    const float* lat = latents + t * 256;
    const float* row = HB + (size_t)(k * 256 + hm) * 256;
    float s = base;
    for (int kk = 0; kk < 256; kk += 4)
      s += row[kk] * lat[kk] + row[kk + 1] * lat[kk + 1] +
           row[kk + 2] * lat[kk + 2] + row[kk + 3] * lat[kk + 3];
    beff[v] = s;
  }
}

// ---------------------------------------------------------------------------
// Kernel A (rewritten): Weff + direct blob write, register accumulators.
// Block = (l, nf, ks, h) tile: 256 threads, thread tid owns row
//   o = nf*32 + (tid>>3), i = ks*16 + h*8 + (tid&7), r = o*256 + i.
// Thread reads its HWh row (256 floats, sequential float4, 1-chunk prefetch),
// accumulates acc[32] (one Weff value per frame) against latents staged in
// LDS transposed [k][f] and read with wave-uniform broadcast ds_read_b128
// (conflict-free). Epilogue adds Wh, splits hi/lo fp16, writes the MFMA
// A-fragment blob directly (coalesced): blob offset for thread = tid + 256*h
// within the (nf,ks,part) 512-half chunk. Replaces old ka_weff + ka2_blob.
// whblob per (tl): [nf(8)][ks(16)][part(2)][lane(64)*8 halves]
// ---------------------------------------------------------------------------
__global__ __launch_bounds__(256) void ka_weff_blob(
    const float* __restrict__ latents, const float* __restrict__ Wh,
    const float* __restrict__ HWh, _Float16* __restrict__ whblob) {
  __shared__ float lat_t[8192];  // [k][f] : 256 x 32
  int tid = threadIdx.x, bid = blockIdx.x;
  int h = bid & 1, ks = (bid >> 1) & 15, nf = (bid >> 5) & 7, l = bid >> 8;

  // stage latents transposed: lat_t[k*32 + f] = latents[f*256 + k]
  {
    int f = tid >> 3, kb = (tid & 7) * 32;
#pragma unroll
    for (int m = 0; m < 32; m += 4) {
      float4 v = *(const float4*)(latents + f * 256 + kb + m);
      lat_t[(kb + m + 0) * 32 + f] = v.x;
      lat_t[(kb + m + 1) * 32 + f] = v.y;
      lat_t[(kb + m + 2) * 32 + f] = v.z;
      lat_t[(kb + m + 3) * 32 + f] = v.w;
    }
  }
  __syncthreads();

  int oo = tid >> 3, jj = tid & 7;
  int o = nf * 32 + oo;
  int i = ks * 16 + h * 8 + jj;
  int r = o * 256 + i;
  const float* rowp = HWh + ((size_t)l * 65536 + (size_t)r) * 256;

  float acc[32];
#pragma unroll
  for (int f = 0; f < 32; ++f) acc[f] = 0.f;

  float curf[16], nxtf[16];
#pragma unroll
  for (int q = 0; q < 4; ++q)
    *(float4*)(curf + q * 4) = *(const float4*)(rowp + q * 4);

  for (int kc = 0; kc < 16; ++kc) {
    if (kc < 15) {
#pragma unroll
      for (int q = 0; q < 4; ++q)
        *(float4*)(nxtf + q * 4) = *(const float4*)(rowp + (kc + 1) * 16 + q * 4);
    }
    const float* lp = lat_t + kc * 512;  // 16 k-rows of 32 f
#pragma unroll
    for (int m = 0; m < 16; ++m) {
      float hw = curf[m];
#pragma unroll
      for (int fq = 0; fq < 8; ++fq) {
        float4 lv = *(const float4*)(lp + m * 32 + fq * 4);
        acc[fq * 4 + 0] += hw * lv.x;
        acc[fq * 4 + 1] += hw * lv.y;
        acc[fq * 4 + 2] += hw * lv.z;
        acc[fq * 4 + 3] += hw * lv.w;
      }
    }
#pragma unroll
    for (int q = 0; q < 16; ++q) curf[q] = nxtf[q];
  }

  float whv = Wh[l * 65536 + r];
  size_t cbase = (size_t)(nf * 16 + ks) * 1024 + (size_t)h * 256 + (size_t)tid;
#pragma unroll
  for (int t = 0; t < 32; ++t) {
    float w = acc[t] + whv;
    _Float16 hi = (_Float16)w;
    _Float16 lo = (_Float16)((w - (float)hi) * LO_SCALE);
    size_t b = (size_t)(t * 3 + l) * 131072 + cbase;
    whblob[b] = hi;
    whblob[b + 512] = lo;
  }
}

// ---------------------------------------------------------------------------
// Kernel B: fused SIREN. Block = one frame x 64 pixels. 4 waves, each owns a
// 64-wide o-slice. Transposed GEMM: D[o][px] = sum_k Weff[o][k]*x[px][k] via
// mfma_f32_32x32x16_f16, split-fp16 (hh -> accA; hl + lh (lo pre-scaled 2048)
// -> accB; result = accA + accB/2048). x kept in LDS as hi/lo fp16 arrays.
// ---------------------------------------------------------------------------
__global__ __launch_bounds__(256, 2) void kb_siren(
    const float* __restrict__ coords, const _Float16* __restrict__ whblob,
    const _Float16* __restrict__ w0blob, const float* __restrict__ beff,
    const float* __restrict__ Wf, const float* __restrict__ bf,
    float* __restrict__ out) {
  __shared__ _Float16 xs_hi[64 * 264];
  __shared__ _Float16 xs_lo[64 * 264];
  __shared__ float wf_s[768];
  __shared__ float red[768];
  int tid = threadIdx.x;
  int bid0 = blockIdx.x;
  int bid = (bid0 & 7) * 256 + (bid0 >> 3);  // XCD swizzle: 4 frames per XCD
  int t = bid >> 6, tile = bid & 63;
  int wv = tid >> 6, lane = tid & 63, col = lane & 31, h = lane >> 5;

  if (tid < 192) *(float4*)(wf_s + tid * 4) = *(const float4*)(Wf + tid * 4);
  if (tid < 64) {
    const float* cp = coords + (size_t)(t * 4096 + tile * 64 + tid) * 3;
    float c0 = cp[0], c1 = cp[1], c2 = cp[2];
    H8 hv, lv, z;
#pragma unroll
    for (int j = 0; j < 8; ++j) { hv.h[j] = (_Float16)0.f; lv.h[j] = (_Float16)0.f; z.h[j] = (_Float16)0.f; }
    _Float16 h0 = (_Float16)c0, h1 = (_Float16)c1, h2 = (_Float16)c2;
    hv.h[0] = h0; hv.h[1] = h1; hv.h[2] = h2;
    lv.h[0] = (_Float16)((c0 - (float)h0) * LO_SCALE);
    lv.h[1] = (_Float16)((c1 - (float)h1) * LO_SCALE);
    lv.h[2] = (_Float16)((c2 - (float)h2) * LO_SCALE);
    *(f16x8*)(xs_hi + tid * 264) = hv.v;
    *(f16x8*)(xs_lo + tid * 264) = lv.v;
    *(f16x8*)(xs_hi + tid * 264 + 8) = z.v;
    *(f16x8*)(xs_lo + tid * 264 + 8) = z.v;
  }
  __syncthreads();

  f32x16 accA[2][2], accB[2][2];

  auto init_bias = [&](int bk) {
    const float* bp = beff + ((t * 4 + bk) << 8) + wv * 64 + h * 4;
#pragma unroll
    for (int fr = 0; fr < 2; ++fr)
#pragma unroll
      for (int rq = 0; rq < 4; ++rq) {
        float4 bvv = *(const float4*)(bp + fr * 32 + rq * 8);
        float ba[4];
        *(float4*)ba = bvv;
#pragma unroll
        for (int q = 0; q < 4; ++q) {
          accA[fr][0][rq * 4 + q] = ba[q];
          accA[fr][1][rq * 4 + q] = ba[q];
          accB[fr][0][rq * 4 + q] = 0.f;
          accB[fr][1][rq * 4 + q] = 0.f;
        }
      }
  };

  auto load_a = [&](const _Float16* blobL, int NS, int ks, f16x8 (&a)[2][2]) {
#pragma unroll
    for (int fr = 0; fr < 2; ++fr) {
      int nf = wv * 2 + fr;
      const _Float16* p = blobL + (size_t)((nf * NS + ks) * 2) * 512 + lane * 8;
      a[fr][0] = *(const f16x8*)p;
      a[fr][1] = *(const f16x8*)(p + 512);
    }
  };

  auto load_b = [&](int ks, f16x8 (&b)[2][2]) {
#pragma unroll
    for (int pf = 0; pf < 2; ++pf) {
      int off = (pf * 32 + col) * 264 + ks * 16 + h * 8;
      b[pf][0] = *(const f16x8*)(xs_hi + off);
      b[pf][1] = *(const f16x8*)(xs_lo + off);
    }
  };

  auto mfma12 = [&](f16x8 (&a)[2][2], f16x8 (&b)[2][2]) {
#pragma unroll
    for (int fr = 0; fr < 2; ++fr)
#pragma unroll
      for (int pf = 0; pf < 2; ++pf) {
        accA[fr][pf] = __builtin_amdgcn_mfma_f32_32x32x16_f16(a[fr][0], b[pf][0], accA[fr][pf], 0, 0, 0);
        accB[fr][pf] = __builtin_amdgcn_mfma_f32_32x32x16_f16(a[fr][0], b[pf][1], accB[fr][pf], 0, 0, 0);
        accB[fr][pf] = __builtin_amdgcn_mfma_f32_32x32x16_f16(a[fr][1], b[pf][0], accB[fr][pf], 0, 0, 0);
      }
  };

  // sine + split + in-register transpose (C rows=o -> B-frag k-contig) + store
  auto epilogue = [&]() {
#pragma unroll
    for (int fr = 0; fr < 2; ++fr)
#pragma unroll
      for (int pf = 0; pf < 2; ++pf)
#pragma unroll
        for (int r = 0; r < 16; ++r)
          accA[fr][pf][r] = __sinf(30.0f * (accA[fr][pf][r] + accB[fr][pf][r] * LO_INV));
    __syncthreads();  // all waves done reading xs for this layer
#pragma unroll
    for (int fr = 0; fr < 2; ++fr)
#pragma unroll
      for (int pf = 0; pf < 2; ++pf)
#pragma unroll
        for (int g = 0; g < 2; ++g) {
          float seq[8];
#pragma unroll
          for (int q = 0; q < 4; ++q) {
            float oa = accA[fr][pf][8 * g + q];       // rows 16g + q + 4h
            float ob = accA[fr][pf][8 * g + 4 + q];   // rows 16g + 8 + q + 4h
            float send = h ? oa : ob;
            float recv = __shfl_xor(send, 32, 64);
            seq[q]     = h ? recv : oa;
            seq[4 + q] = h ? ob : recv;
          }
          H8 hv, lv;
#pragma unroll
          for (int j = 0; j < 8; ++j) {
            _Float16 hi = (_Float16)seq[j];
            hv.h[j] = hi;
            lv.h[j] = (_Float16)((seq[j] - (float)hi) * LO_SCALE);
          }
          int off = (pf * 32 + col) * 264 + wv * 64 + fr * 32 + g * 16 + h * 8;
          *(f16x8*)(xs_hi + off) = hv.v;
          *(f16x8*)(xs_lo + off) = lv.v;
        }
    __syncthreads();
  };

  // ---- layer 0 (k=16, mostly zero-padded; coords staged in xs[.., 0..15])
  init_bias(0);
  {
    f16x8 a[2][2], b[2][2];
    load_a(w0blob + (size_t)t * 8192, 1, 0, a);
    load_b(0, b);
    mfma12(a, b);
  }
  epilogue();

  // ---- hidden layers
  for (int li = 0; li < 3; ++li) {
    init_bias(li + 1);
    const _Float16* bl = whblob + (size_t)(t * 3 + li) * 131072;
#pragma unroll
    for (int ks = 0; ks < 16; ++ks) {
      f16x8 a[2][2], b[2][2];
      load_a(bl, 16, ks, a);
      load_b(ks, b);
      mfma12(a, b);
    }
    epilogue();
  }

  // ---- final linear (3 outputs), VALU from LDS
  {
    float pc0 = 0.f, pc1 = 0.f, pc2 = 0.f;
    int px = tid & 63, kq = tid >> 6;
#pragma unroll
    for (int cc = 0; cc < 8; ++cc) {
      int k0 = kq * 64 + cc * 8;
      H8 hv, lv;
      hv.v = *(const f16x8*)(xs_hi + px * 264 + k0);
      lv.v = *(const f16x8*)(xs_lo + px * 264 + k0);
#pragma unroll
      for (int j = 0; j < 8; ++j) {
        float xv = (float)hv.h[j] + (float)lv.h[j] * LO_INV;
        pc0 += xv * wf_s[k0 + j];
        pc1 += xv * wf_s[256 + k0 + j];
        pc2 += xv * wf_s[512 + k0 + j];
      }
    }
    red[(kq * 64 + px) * 3 + 0] = pc0;
    red[(kq * 64 + px) * 3 + 1] = pc1;
    red[(kq * 64 + px) * 3 + 2] = pc2;
    __syncthreads();
    if (tid < 192) {
      int p2 = tid / 3, c = tid - p2 * 3;
      float s = red[p2 * 3 + c] + red[192 + p2 * 3 + c] +
                red[384 + p2 * 3 + c] + red[576 + p2 * 3 + c] + bf[c];
      out[(size_t)(t * 4096 + tile * 64 + p2) * 3 + c] = s;
    }
  }
}

// ---------------------------------------------------------------------------
extern "C" void kernel_launch(void* const* d_in, const int* in_sizes, int n_in,
                              void* d_out, int out_size, void* d_ws, size_t ws_size,
                              hipStream_t stream) {
  const float* coords  = (const float*)d_in[0];
  const float* latents = (const float*)d_in[1];
  const float* W0      = (const float*)d_in[2];
  const float* b0      = (const float*)d_in[3];
  const float* Wh      = (const float*)d_in[4];
  const float* bh      = (const float*)d_in[5];
  const float* Wf      = (const float*)d_in[6];
  const float* bf      = (const float*)d_in[7];
  const float* HW0     = (const float*)d_in[8];
  const float* HWh     = (const float*)d_in[9];
  const float* HB      = (const float*)d_in[10];
  float* outp = (float*)d_out;

  char* w = (char*)d_ws;
  _Float16* whblob = (_Float16*)w;                   // 12,582,912 halves
  _Float16* w0blob = (_Float16*)(w + 25165824);      // 262,144 halves
  float*    beff   = (float*)(w + 25690112);         // 32,768 floats

  kc_small<<<256, 256, 0, stream>>>(latents, W0, b0, bh, HW0, HB, w0blob, beff);
  ka_weff_blob<<<768, 256, 0, stream>>>(latents, Wh, HWh, whblob);
  kb_siren<<<2048, 256, 0, stream>>>(coords, whblob, w0blob, beff, Wf, bf, outp);
}

// Round 3
// 242.146 us; speedup vs baseline: 1.5209x; 1.0177x over previous
//
#include <hip/hip_runtime.h>
#include <cstdint>
#include <cstddef>

typedef __attribute__((ext_vector_type(8))) _Float16 f16x8;
typedef __attribute__((ext_vector_type(16))) float f32x16;

#define LO_SCALE 2048.0f
#define LO_INV   (1.0f / 2048.0f)

union H8 { f16x8 v; _Float16 h[8]; };

// ---------------------------------------------------------------------------
// Kernel C: layer-0 effective weights (fragment blob) + all effective biases
// w0blob layout per t: [nf(8)][part(2)][lane(64)*8 halves]  (1KB chunks)
// beff layout: [t][k(4)][256] fp32,  k=0: b0+hb0, k>=1: bh[k-1]+hb[k]
// ---------------------------------------------------------------------------
__global__ __launch_bounds__(256) void kc_small(
    const float* __restrict__ latents, const float* __restrict__ W0,
    const float* __restrict__ b0, const float* __restrict__ bh,
    const float* __restrict__ HW0, const float* __restrict__ HB,
    _Float16* __restrict__ w0blob, float* __restrict__ beff) {
  int id = blockIdx.x * 256 + threadIdx.x;
  if (id < 32768) {
    int t = id >> 10, rem = id & 1023;
    int r2 = rem & 127, part = r2 >> 6, lane = r2 & 63;
    int nf = rem >> 7;
    int o = nf * 32 + (lane & 31), kc = lane >> 5;
    const float* lat = latents + t * 256;
    H8 outv;
#pragma unroll
    for (int j = 0; j < 8; ++j) outv.h[j] = (_Float16)0.0f;
#pragma unroll
    for (int j = 0; j < 8; ++j) {
      int i = kc * 8 + j;
      if (i < 3) {
        const float* row = HW0 + (o * 3 + i) * 256;
        float s = W0[o * 3 + i];
        for (int k = 0; k < 256; k += 4)
          s += row[k] * lat[k] + row[k + 1] * lat[k + 1] +
               row[k + 2] * lat[k + 2] + row[k + 3] * lat[k + 3];
        _Float16 hi = (_Float16)s;
        outv.h[j] = part ? (_Float16)((s - (float)hi) * LO_SCALE) : hi;
      }
    }
    *(f16x8*)(w0blob + (size_t)id * 8) = outv.v;
  } else {
    int v = id - 32768;
    int t = v >> 10, k = (v >> 8) & 3, hm = v & 255;
    float base = (k == 0) ? b0[hm] : bh[(k - 1) * 256 + hm];
    const float* lat = latents + t * 256;
    const float* row = HB + (size_t)(k * 256 + hm) * 256;
    float s = base;
    for (int kk = 0; kk < 256; kk += 4)
      s += row[kk] * lat[kk] + row[kk + 1] * lat[kk + 1] +
           row[kk + 2] * lat[kk + 2] + row[kk + 3] * lat[kk + 3];
    beff[v] = s;
  }
}

// ---------------------------------------------------------------------------
// Kernel A: Weff + direct blob write, register accumulators.
// Block = (l, nf, ks, h) tile: 256 threads, thread tid owns row
//   o = nf*32 + (tid>>3), i = ks*16 + h*8 + (tid&7), r = o*256 + i.
// Thread reads its HWh row (256 floats, sequential float4, 1-chunk prefetch),
// accumulates acc[32] (one Weff value per frame) against latents staged in
// LDS transposed [k][f] (wave-uniform broadcast reads, conflict-free).
// Epilogue adds Wh, splits hi/lo fp16, writes the MFMA A-fragment blob
// directly. whblob per (tl): [nf(8)][ks(16)][part(2)][lane(64)*8 halves]
// ---------------------------------------------------------------------------
__global__ __launch_bounds__(256) void ka_weff_blob(
    const float* __restrict__ latents, const float* __restrict__ Wh,
    const float* __restrict__ HWh, _Float16* __restrict__ whblob) {
  __shared__ float lat_t[8192];  // [k][f] : 256 x 32
  int tid = threadIdx.x, bid = blockIdx.x;
  int h = bid & 1, ks = (bid >> 1) & 15, nf = (bid >> 5) & 7, l = bid >> 8;

  {
    int f = tid >> 3, kb = (tid & 7) * 32;
#pragma unroll
    for (int m = 0; m < 32; m += 4) {
      float4 v = *(const float4*)(latents + f * 256 + kb + m);
      lat_t[(kb + m + 0) * 32 + f] = v.x;
      lat_t[(kb + m + 1) * 32 + f] = v.y;
      lat_t[(kb + m + 2) * 32 + f] = v.z;
      lat_t[(kb + m + 3) * 32 + f] = v.w;
    }
  }
  __syncthreads();

  int oo = tid >> 3, jj = tid & 7;
  int o = nf * 32 + oo;
  int i = ks * 16 + h * 8 + jj;
  int r = o * 256 + i;
  const float* rowp = HWh + ((size_t)l * 65536 + (size_t)r) * 256;

  float acc[32];
#pragma unroll
  for (int f = 0; f < 32; ++f) acc[f] = 0.f;

  float curf[16], nxtf[16];
#pragma unroll
  for (int q = 0; q < 4; ++q)
    *(float4*)(curf + q * 4) = *(const float4*)(rowp + q * 4);

  for (int kc = 0; kc < 16; ++kc) {
    if (kc < 15) {
#pragma unroll
      for (int q = 0; q < 4; ++q)
        *(float4*)(nxtf + q * 4) = *(const float4*)(rowp + (kc + 1) * 16 + q * 4);
    }
    const float* lp = lat_t + kc * 512;
#pragma unroll
    for (int m = 0; m < 16; ++m) {
      float hw = curf[m];
#pragma unroll
      for (int fq = 0; fq < 8; ++fq) {
        float4 lv = *(const float4*)(lp + m * 32 + fq * 4);
        acc[fq * 4 + 0] += hw * lv.x;
        acc[fq * 4 + 1] += hw * lv.y;
        acc[fq * 4 + 2] += hw * lv.z;
        acc[fq * 4 + 3] += hw * lv.w;
      }
    }
#pragma unroll
    for (int q = 0; q < 16; ++q) curf[q] = nxtf[q];
  }

  float whv = Wh[l * 65536 + r];
  size_t cbase = (size_t)(nf * 16 + ks) * 1024 + (size_t)h * 256 + (size_t)tid;
#pragma unroll
  for (int t = 0; t < 32; ++t) {
    float w = acc[t] + whv;
    _Float16 hi = (_Float16)w;
    _Float16 lo = (_Float16)((w - (float)hi) * LO_SCALE);
    size_t b = (size_t)(t * 3 + l) * 131072 + cbase;
    whblob[b] = hi;
    whblob[b + 512] = lo;
  }
}

// ---------------------------------------------------------------------------
// Kernel B: fused SIREN. Block = one frame x 64 pixels, 8 waves (512 thr),
// each wave owns a 32-wide o-slice (nf = wave id). Transposed GEMM:
// D[o][px] = sum_k Weff[o][k]*x[px][k] via mfma_f32_32x32x16_f16, split-fp16
// (hh -> accA; hl + lh (lo pre-scaled 2048) -> accB; result = accA+accB/2048).
// x in LDS as hi/lo fp16 arrays. 75KB LDS -> 2 blocks/CU = 4 waves/SIMD.
// ---------------------------------------------------------------------------
__global__ __launch_bounds__(512, 4) void kb_siren(
    const float* __restrict__ coords, const _Float16* __restrict__ whblob,
    const _Float16* __restrict__ w0blob, const float* __restrict__ beff,
    const float* __restrict__ Wf, const float* __restrict__ bf,
    float* __restrict__ out) {
  __shared__ _Float16 xs_hi[64 * 264];
  __shared__ _Float16 xs_lo[64 * 264];
  __shared__ float wf_s[768];
  __shared__ float red[1536];
  int tid = threadIdx.x;
  int bid0 = blockIdx.x;
  int bid = (bid0 & 7) * 256 + (bid0 >> 3);  // XCD swizzle: 4 frames per XCD
  int t = bid >> 6, tile = bid & 63;
  int wv = tid >> 6, lane = tid & 63, col = lane & 31, h = lane >> 5;

  if (tid < 192) *(float4*)(wf_s + tid * 4) = *(const float4*)(Wf + tid * 4);
  if (tid < 64) {
    const float* cp = coords + (size_t)(t * 4096 + tile * 64 + tid) * 3;
    float c0 = cp[0], c1 = cp[1], c2 = cp[2];
    H8 hv, lv, z;
#pragma unroll
    for (int j = 0; j < 8; ++j) { hv.h[j] = (_Float16)0.f; lv.h[j] = (_Float16)0.f; z.h[j] = (_Float16)0.f; }
    _Float16 h0 = (_Float16)c0, h1 = (_Float16)c1, h2 = (_Float16)c2;
    hv.h[0] = h0; hv.h[1] = h1; hv.h[2] = h2;
    lv.h[0] = (_Float16)((c0 - (float)h0) * LO_SCALE);
    lv.h[1] = (_Float16)((c1 - (float)h1) * LO_SCALE);
    lv.h[2] = (_Float16)((c2 - (float)h2) * LO_SCALE);
    *(f16x8*)(xs_hi + tid * 264) = hv.v;
    *(f16x8*)(xs_lo + tid * 264) = lv.v;
    *(f16x8*)(xs_hi + tid * 264 + 8) = z.v;
    *(f16x8*)(xs_lo + tid * 264 + 8) = z.v;
  }
  __syncthreads();

  f32x16 accA[2], accB[2];  // [pf]

  auto init_bias = [&](int bk) {
    const float* bp = beff + ((t * 4 + bk) << 8) + wv * 32 + h * 4;
#pragma unroll
    for (int rq = 0; rq < 4; ++rq) {
      float4 bvv = *(const float4*)(bp + rq * 8);
      float ba[4];
      *(float4*)ba = bvv;
#pragma unroll
      for (int q = 0; q < 4; ++q) {
        accA[0][rq * 4 + q] = ba[q];
        accA[1][rq * 4 + q] = ba[q];
        accB[0][rq * 4 + q] = 0.f;
        accB[1][rq * 4 + q] = 0.f;
      }
    }
  };

  auto load_a = [&](const _Float16* blobL, int NS, int ks, f16x8 (&a)[2]) {
    const _Float16* p = blobL + (size_t)((wv * NS + ks) * 2) * 512 + lane * 8;
    a[0] = *(const f16x8*)p;
    a[1] = *(const f16x8*)(p + 512);
  };

  auto load_b = [&](int ks, f16x8 (&b)[2][2]) {
#pragma unroll
    for (int pf = 0; pf < 2; ++pf) {
      int off = (pf * 32 + col) * 264 + ks * 16 + h * 8;
      b[pf][0] = *(const f16x8*)(xs_hi + off);
      b[pf][1] = *(const f16x8*)(xs_lo + off);
    }
  };

  auto mfma6 = [&](f16x8 (&a)[2], f16x8 (&b)[2][2]) {
    accA[0] = __builtin_amdgcn_mfma_f32_32x32x16_f16(a[0], b[0][0], accA[0], 0, 0, 0);
    accA[1] = __builtin_amdgcn_mfma_f32_32x32x16_f16(a[0], b[1][0], accA[1], 0, 0, 0);
    accB[0] = __builtin_amdgcn_mfma_f32_32x32x16_f16(a[0], b[0][1], accB[0], 0, 0, 0);
    accB[1] = __builtin_amdgcn_mfma_f32_32x32x16_f16(a[0], b[1][1], accB[1], 0, 0, 0);
    accB[0] = __builtin_amdgcn_mfma_f32_32x32x16_f16(a[1], b[0][0], accB[0], 0, 0, 0);
    accB[1] = __builtin_amdgcn_mfma_f32_32x32x16_f16(a[1], b[1][0], accB[1], 0, 0, 0);
  };

  // sine + split + in-register transpose (C rows=o -> B-frag k-contig) + store
  auto epilogue = [&]() {
#pragma unroll
    for (int pf = 0; pf < 2; ++pf)
#pragma unroll
      for (int r = 0; r < 16; ++r)
        accA[pf][r] = __sinf(30.0f * (accA[pf][r] + accB[pf][r] * LO_INV));
    __syncthreads();  // all waves done reading xs for this layer
#pragma unroll
    for (int pf = 0; pf < 2; ++pf)
#pragma unroll
      for (int g = 0; g < 2; ++g) {
        float seq[8];
#pragma unroll
        for (int q = 0; q < 4; ++q) {
          float oa = accA[pf][8 * g + q];       // rows 8g*2 + q + 4h
          float ob = accA[pf][8 * g + 4 + q];   // rows +8
          float send = h ? oa : ob;
          float recv = __shfl_xor(send, 32, 64);
          seq[q]     = h ? recv : oa;
          seq[4 + q] = h ? ob : recv;
        }
        H8 hv, lv;
#pragma unroll
        for (int j = 0; j < 8; ++j) {
          _Float16 hi = (_Float16)seq[j];
          hv.h[j] = hi;
          lv.h[j] = (_Float16)((seq[j] - (float)hi) * LO_SCALE);
        }
        int off = (pf * 32 + col) * 264 + wv * 32 + g * 16 + h * 8;
        *(f16x8*)(xs_hi + off) = hv.v;
        *(f16x8*)(xs_lo + off) = lv.v;
      }
    __syncthreads();
  };

  // ---- layer 0 (k=16, mostly zero-padded; coords staged in xs[.., 0..15])
  init_bias(0);
  {
    f16x8 a[2], b[2][2];
    load_a(w0blob + (size_t)t * 8192, 1, 0, a);
    load_b(0, b);
    mfma6(a, b);
  }
  epilogue();

  // ---- hidden layers
  for (int li = 0; li < 3; ++li) {
    init_bias(li + 1);
    const _Float16* bl = whblob + (size_t)(t * 3 + li) * 131072;
#pragma unroll
    for (int ks = 0; ks < 16; ++ks) {
      f16x8 a[2], b[2][2];
      load_a(bl, 16, ks, a);
      load_b(ks, b);
      mfma6(a, b);
    }
    epilogue();
  }

  // ---- final linear (3 outputs), VALU from LDS; 8 k-groups of 32
  {
    float pc0 = 0.f, pc1 = 0.f, pc2 = 0.f;
    int px = tid & 63, kq = tid >> 6;
#pragma unroll
    for (int cc = 0; cc < 4; ++cc) {
      int k0 = kq * 32 + cc * 8;
      H8 hv, lv;
      hv.v = *(const f16x8*)(xs_hi + px * 264 + k0);
      lv.v = *(const f16x8*)(xs_lo + px * 264 + k0);
#pragma unroll
      for (int j = 0; j < 8; ++j) {
        float xv = (float)hv.h[j] + (float)lv.h[j] * LO_INV;
        pc0 += xv * wf_s[k0 + j];
        pc1 += xv * wf_s[256 + k0 + j];
        pc2 += xv * wf_s[512 + k0 + j];
      }
    }
    red[(kq * 64 + px) * 3 + 0] = pc0;
    red[(kq * 64 + px) * 3 + 1] = pc1;
    red[(kq * 64 + px) * 3 + 2] = pc2;
    __syncthreads();
    if (tid < 192) {
      int p2 = tid / 3, c = tid - p2 * 3;
      float s = bf[c];
#pragma unroll
      for (int q = 0; q < 8; ++q) s += red[(q * 64 + p2) * 3 + c];
      out[(size_t)(t * 4096 + tile * 64 + p2) * 3 + c] = s;
    }
  }
}

// ---------------------------------------------------------------------------
extern "C" void kernel_launch(void* const* d_in, const int* in_sizes, int n_in,
                              void* d_out, int out_size, void* d_ws, size_t ws_size,
                              hipStream_t stream) {
  const float* coords  = (const float*)d_in[0];
  const float* latents = (const float*)d_in[1];
  const float* W0      = (const float*)d_in[2];
  const float* b0      = (const float*)d_in[3];
  const float* Wh      = (const float*)d_in[4];
  const float* bh      = (const float*)d_in[5];
  const float* Wf      = (const float*)d_in[6];
  const float* bf      = (const float*)d_in[7];
  const float* HW0     = (const float*)d_in[8];
  const float* HWh     = (const float*)d_in[9];
  const float* HB      = (const float*)d_in[10];
  float* outp = (float*)d_out;

  char* w = (char*)d_ws;
  _Float16* whblob = (_Float16*)w;                   // 12,582,912 halves
  _Float16* w0blob = (_Float16*)(w + 25165824);      // 262,144 halves
  float*    beff   = (float*)(w + 25690112);         // 32,768 floats

  kc_small<<<256, 256, 0, stream>>>(latents, W0, b0, bh, HW0, HB, w0blob, beff);
  ka_weff_blob<<<768, 256, 0, stream>>>(latents, Wh, HWh, whblob);
  kb_siren<<<2048, 512, 0, stream>>>(coords, whblob, w0blob, beff, Wf, bf, outp);
}